// Round 8
// baseline (2895.196 us; speedup 1.0000x reference)
//
#include <hip/hip_runtime.h>
#include <cmath>

// ---------------------------------------------------------------------------
// RegRNN: out[b,t,:] = h_t ; h_t = tanh(xproj[b,t,:] + h_{t-1} @ Whh^T)
// xproj = seq @ Wih^T + bias   (Wih/Whh hard-concrete gated, fp16)
//
// Phase A: MFMA fp16 GEMM writes xproj straight into d_out (in-place reuse).
// Phase B: persistent kernel, 32 WGs = 4 batch-groups x 8 j-slices (128 cols).
//          Whh slice register-resident. h exchange via TAGGED WORDS:
//          each 8B word = [tag:u32 = step | 2 fp16]. 8B atomic load is
//          single-copy atomic -> tag+data arrive together, so the consumer
//          POLLS THE DATA ITSELF (tag >= t). One L3 round trip per handoff:
//          no vmcnt drain, no seqno, no separate data load.
//          Tagged chunk = 256 u64 (2KB): word j of lane l at j*64 + l.
//          Consumer wave w loads 7 peers' chunk i*4+w (4 words/lane),
//          strips tags -> LDS hlds; own slice short-circuited from tile.
//          2 barriers/step (hlds-ready D, tile-done B).
//          WAR safety: X overwrites parity (t+1)&1 (tag t+1) only after its
//          iter-t poll saw tag-t from every peer's wave-w chunk; peer Y's
//          tag-t stores issue after Y's barriers B>D at iter t-1, hence
//          after ALL Y's reads of parity (t+1)&1 completed (retry loop
//          consumes every load). Tags monotone (parity p: p, p+2, ...);
//          grounded at t=0 by prep-zeroed tags (0 >= 0, data 0 = h0).
// ---------------------------------------------------------------------------

typedef _Float16 v8h __attribute__((ext_vector_type(8)));
typedef float    v4f __attribute__((ext_vector_type(4)));
typedef unsigned long long u64;
typedef unsigned int u32;

#define BB 64
#define TT 512
#define HH 1024
#define OUT_MAIN (BB * TT * HH) // 33554432
// ws layout (bytes)
#define OFF_WIH  0u
#define OFF_WHH  (2u << 20)
#define OFF_BIAS (4u << 20)
#define OFF_HBUF ((4u << 20) + 8192u)   // tagged: 2 par * 4 groups * 32 chunks * 256 u64 = 512KB

#define ALD(p)    __hip_atomic_load((p),        __ATOMIC_RELAXED, __HIP_MEMORY_SCOPE_AGENT)
#define AST(p, v) __hip_atomic_store((p), (v),  __ATOMIC_RELAXED, __HIP_MEMORY_SCOPE_AGENT)

__device__ __forceinline__ float hc_gate(float x) {
    float s = 1.0f / (1.0f + __expf(-x));
    float g = s * 1.2f - 0.1f;              // sigmoid*(LB-LA)+LA
    return fminf(1.0f, fmaxf(0.0f, g));
}

__device__ __forceinline__ float fast_tanh(float x) {
    // tanh(x) = 1 - 2/(e^{2x}+1); exp->inf and ->0 both saturate correctly.
    float e = __expf(2.0f * x);
    return 1.0f - 2.0f * __builtin_amdgcn_rcpf(e + 1.0f);
}

// ---------------- prep: gate+cast weights, bias, zero tagged h buffer ------
__global__ void prep_kernel(const float* __restrict__ w_ih, const float* __restrict__ w_ih_mask,
                            const float* __restrict__ w_hh, const float* __restrict__ w_hh_mask,
                            const float* __restrict__ b_ih, const float* __restrict__ b_ih_mask,
                            const float* __restrict__ b_hh, const float* __restrict__ b_hh_mask,
                            _Float16* __restrict__ Wih, _Float16* __restrict__ Whh,
                            float* __restrict__ bias, u64* __restrict__ hbt) {
    const int idx = blockIdx.x * 256 + threadIdx.x;   // grid 4096*256 = 1048576 exact
    Wih[idx] = (_Float16)(hc_gate(w_ih_mask[idx]) * w_ih[idx]);
    Whh[idx] = (_Float16)(hc_gate(w_hh_mask[idx]) * w_hh[idx]);
    if (idx < HH)
        bias[idx] = hc_gate(b_ih_mask[idx]) * b_ih[idx] + hc_gate(b_hh_mask[idx]) * b_hh[idx];
    if (idx < 65536) hbt[idx] = 0ull;   // tag 0, data 0: h0 = 0, t=0 poll passes
}

// ---------------- Phase A: xproj GEMM --------------------------------------
// C[m,n] = sum_k seq[m,k]*Wih[n,k] + bias[n], 128x128 tile, BK=32, 256 thr.
__global__ __launch_bounds__(256, 2) void gemm_xproj(const float* __restrict__ seq,
                                                     const _Float16* __restrict__ Wih,
                                                     const float* __restrict__ bias,
                                                     float* __restrict__ out) {
    __shared__ _Float16 As[128][40];   // +8 pad: row stride 80B = 20 banks -> 2-way (free)
    __shared__ _Float16 Bs[128][40];

    const int tid  = threadIdx.x;
    const int lane = tid & 63;
    const int w    = tid >> 6;
    const int bid  = blockIdx.x;
    const int m0 = (bid >> 3) * 128;
    const int n0 = (bid & 7) * 128;
    const int mw = (w >> 1) * 64, nw = (w & 1) * 64;

    const int sr = tid >> 1;            // staging row 0..127
    const int sc = (tid & 1) * 16;      // staging col 0/16

    const float*    aSrc = seq + (m0 + sr) * HH + sc;
    const _Float16* bSrc = Wih + (n0 + sr) * HH + sc;

    const v4f vzero = {0.f, 0.f, 0.f, 0.f};
    v4f acc[4][4];
#pragma unroll
    for (int i = 0; i < 4; i++)
#pragma unroll
        for (int j = 0; j < 4; j++) acc[i][j] = vzero;

    const int arow = mw + (lane & 15);
    const int brow = nw + (lane & 15);
    const int kq   = (lane >> 4) * 8;

    for (int k0 = 0; k0 < HH; k0 += 32) {
        // stage A (fp32 -> fp16) and B
        float4 f0 = *(const float4*)(aSrc + 0);
        float4 f1 = *(const float4*)(aSrc + 4);
        float4 f2 = *(const float4*)(aSrc + 8);
        float4 f3 = *(const float4*)(aSrc + 12);
        v8h a0 = {(_Float16)f0.x, (_Float16)f0.y, (_Float16)f0.z, (_Float16)f0.w,
                  (_Float16)f1.x, (_Float16)f1.y, (_Float16)f1.z, (_Float16)f1.w};
        v8h a1 = {(_Float16)f2.x, (_Float16)f2.y, (_Float16)f2.z, (_Float16)f2.w,
                  (_Float16)f3.x, (_Float16)f3.y, (_Float16)f3.z, (_Float16)f3.w};
        v8h b0 = *(const v8h*)(bSrc + 0);
        v8h b1 = *(const v8h*)(bSrc + 8);
        *(v8h*)&As[sr][sc]     = a0;
        *(v8h*)&As[sr][sc + 8] = a1;
        *(v8h*)&Bs[sr][sc]     = b0;
        *(v8h*)&Bs[sr][sc + 8] = b1;
        __syncthreads();

        v8h af[4], bf[4];
#pragma unroll
        for (int mi = 0; mi < 4; mi++) af[mi] = *(const v8h*)&As[mi * 16 + arow][kq];
#pragma unroll
        for (int ni = 0; ni < 4; ni++) bf[ni] = *(const v8h*)&Bs[ni * 16 + brow][kq];
#pragma unroll
        for (int mi = 0; mi < 4; mi++)
#pragma unroll
            for (int ni = 0; ni < 4; ni++)
                acc[mi][ni] = __builtin_amdgcn_mfma_f32_16x16x32_f16(af[mi], bf[ni], acc[mi][ni], 0, 0, 0);
        __syncthreads();
        aSrc += 32;
        bSrc += 32;
    }

    // epilogue: D col = lane&15 (n), row = (lane>>4)*4 + reg (m)  [m89 layout]
    const int colb = lane & 15;
    const int rowq = (lane >> 4) * 4;
#pragma unroll
    for (int ni = 0; ni < 4; ni++) {
        const int col = n0 + nw + ni * 16 + colb;
        const float bz = bias[col];
#pragma unroll
        for (int mi = 0; mi < 4; mi++) {
            const int row = m0 + mw + mi * 16 + rowq;
#pragma unroll
            for (int r = 0; r < 4; r++)
                out[(row + r) * HH + col] = acc[mi][ni][r] + bz;
        }
    }
}

// ---------------- Phase B: persistent recurrence ---------------------------
// 32 WGs: g = bid>>3 (batch group of 16), jw = bid&7 (128 output cols).
// Whh slice: Wf[64] v8h = 256 regs/thread (2 col-fragments x 32 k-chunks).
// Tagged hbuf: chunk c of (parity,g) at ((par*4+g)*32 + c)*256 u64;
//   word j of lane l at +j*64+l; word = [tag:u32 | halves 2j,2j+1].
//   chunk c = slice (c>>2), wave-row (c&3). hlds chunk = 128 u64 (untagged).
__global__ __launch_bounds__(256, 1) void rnn_steps(const _Float16* __restrict__ Whh,
                                                    float* __restrict__ out,
                                                    u64* __restrict__ hbt) {
    __shared__ _Float16 tile[16 * 128];          // 4 KB, XOR-swizzled transpose buffer
    __shared__ __align__(16) u64 hlds[32 * 128]; // 32 KB fragment-ready h

    const int tid  = threadIdx.x;
    const int lane = tid & 63;
    const int w    = tid >> 6;
    const int bid  = blockIdx.x;
    const int g    = bid >> 3;
    const int jw   = bid & 7;

    const int l15 = lane & 15;
    const int kq  = (lane >> 4) * 8;      // k sub-offset of this lane's fragment
    const int bq  = (lane >> 4) * 4;      // D row base = local batch index

    const int col0 = jw * 128 + w * 32 + l15;   // ni=0 output column (== B row n)

    // Whh fragments: Wf[c*2+ni] = Whh[(col0+16*ni)*1024 + c*32 + kq .. +8]
    v8h Wf[64];
    {
        const _Float16* w0 = Whh + col0 * 1024 + kq;
        const _Float16* w1 = Whh + (col0 + 16) * 1024 + kq;
#pragma unroll
        for (int c = 0; c < 32; c++) {
            Wf[c * 2 + 0] = *(const v8h*)(w0 + c * 32);
            Wf[c * 2 + 1] = *(const v8h*)(w1 + c * 32);
        }
    }

    // own-slice hlds init (h0 = 0); peer chunks come from tagged hbuf (zeroed).
    {
        u64* q = &hlds[(jw * 4 + w) * 128 + lane * 2];
        q[0] = 0ull; q[1] = 0ull;
    }
    // (first iteration's barrier D orders this vs. MFMA reads)

    // xproj prefetch for t=0 (gemm output staged in d_out)
    float xp[2][4];
#pragma unroll
    for (int r = 0; r < 4; r++) {
        const float* xs = out + ((g * 16 + bq + r) * TT + 0) * HH + col0;
        xp[0][r] = xs[0];
        xp[1][r] = xs[16];
    }

    for (int t = 0; t < TT; t++) {
        // ---- consumer: poll 7 peers' tagged chunk-row w (tag IS the handoff)
        const u64* tb = hbt + (u64)(((t & 1) * 4 + g) * 32) * 256;
        u64 d[8][4];
#pragma unroll
        for (int i = 0; i < 8; i++) {
            if (i != jw) {
                const u64* p = tb + (i * 4 + w) * 256 + lane;
                d[i][0] = ALD(p);       d[i][1] = ALD(p + 64);
                d[i][2] = ALD(p + 128); d[i][3] = ALD(p + 192);
            }
        }
        const u32 tt = (u32)t;
        for (;;) {
            int ok = 1;
#pragma unroll
            for (int i = 0; i < 8; i++) {
                if (i != jw) {
                    u32 m0 = (u32)(d[i][0] >> 32), m1 = (u32)(d[i][1] >> 32);
                    u32 m2 = (u32)(d[i][2] >> 32), m3 = (u32)(d[i][3] >> 32);
                    u32 a = m0 < m1 ? m0 : m1;
                    u32 b = m2 < m3 ? m2 : m3;
                    u32 mn = a < b ? a : b;
                    ok &= (mn >= tt) ? 1 : 0;
                }
            }
            if (__all(ok)) break;
            __builtin_amdgcn_s_sleep(1);
#pragma unroll
            for (int i = 0; i < 8; i++) {
                if (i != jw) {
                    const u64* p = tb + (i * 4 + w) * 256 + lane;
                    d[i][0] = ALD(p);       d[i][1] = ALD(p + 64);
                    d[i][2] = ALD(p + 128); d[i][3] = ALD(p + 192);
                }
            }
        }
        asm volatile("" ::: "memory");

        // ---- strip tags -> hlds (fragment halves 0..7 = lo32 of words 0..3)
#pragma unroll
        for (int i = 0; i < 8; i++) {
            if (i != jw) {
                u64 lo = (d[i][0] & 0xffffffffull) | (d[i][1] << 32);
                u64 hi = (d[i][2] & 0xffffffffull) | (d[i][3] << 32);
                u64* q = &hlds[(i * 4 + w) * 128 + lane * 2];
                q[0] = lo;
                q[1] = hi;
            }
        }
        __syncthreads();   // D: full h_{t-1} staged in hlds

        // ---- MFMA over 32 chunks from LDS (contiguous 16B reads, conflict-free)
        v4f aA0 = {0.f, 0.f, 0.f, 0.f}, aA1 = aA0, aB0 = aA0, aB1 = aA0;
#pragma unroll
        for (int cc = 0; cc < 8; cc++) {
            const u64* q = &hlds[cc * 512 + lane * 2];
            v8h h0 = *(const v8h*)(q);
            v8h h1 = *(const v8h*)(q + 128);
            v8h h2 = *(const v8h*)(q + 256);
            v8h h3 = *(const v8h*)(q + 384);
            aA0 = __builtin_amdgcn_mfma_f32_16x16x32_f16(h0, Wf[(cc * 4 + 0) * 2 + 0], aA0, 0, 0, 0);
            aA1 = __builtin_amdgcn_mfma_f32_16x16x32_f16(h0, Wf[(cc * 4 + 0) * 2 + 1], aA1, 0, 0, 0);
            aB0 = __builtin_amdgcn_mfma_f32_16x16x32_f16(h1, Wf[(cc * 4 + 1) * 2 + 0], aB0, 0, 0, 0);
            aB1 = __builtin_amdgcn_mfma_f32_16x16x32_f16(h1, Wf[(cc * 4 + 1) * 2 + 1], aB1, 0, 0, 0);
            aA0 = __builtin_amdgcn_mfma_f32_16x16x32_f16(h2, Wf[(cc * 4 + 2) * 2 + 0], aA0, 0, 0, 0);
            aA1 = __builtin_amdgcn_mfma_f32_16x16x32_f16(h2, Wf[(cc * 4 + 2) * 2 + 1], aA1, 0, 0, 0);
            aB0 = __builtin_amdgcn_mfma_f32_16x16x32_f16(h3, Wf[(cc * 4 + 3) * 2 + 0], aB0, 0, 0, 0);
            aB1 = __builtin_amdgcn_mfma_f32_16x16x32_f16(h3, Wf[(cc * 4 + 3) * 2 + 1], aB1, 0, 0, 0);
        }
        const v4f av0 = aA0 + aB0;
        const v4f av1 = aA1 + aB1;

        // ---- tanh + LDS transpose into fragment-ready order (XOR-swizzled)
        float hv[2][4];
#pragma unroll
        for (int r = 0; r < 4; r++) {
            hv[0][r] = fast_tanh(xp[0][r] + av0[r]);
            hv[1][r] = fast_tanh(xp[1][r] + av1[r]);
            const int row = bq + r;
            const int sw  = (row & 7) << 4;
            char* base = (char*)tile + row * 256;
            *(_Float16*)(base + (((w * 32 + l15) * 2) ^ sw))      = (_Float16)hv[0][r];
            *(_Float16*)(base + (((w * 32 + 16 + l15) * 2) ^ sw)) = (_Float16)hv[1][r];
        }
        __syncthreads();   // B: transpose tile complete (also fences hlds WAR)

        // ---- producer wave w: tagged chunk jw*4+w -> global + hlds (self)
        {
            const int row = lane & 15;
            const int cb  = (w * 32 + (lane >> 4) * 8) * 2;   // byte col offset in tile row
            union { v8h v; u64 u[2]; } uu;
            uu.v = *(const v8h*)((const char*)tile + row * 256 + (cb ^ ((row & 7) << 4)));
            u64* dstb = hbt + (u64)((((t + 1) & 1) * 4 + g) * 32 + jw * 4 + w) * 256 + lane;
            const u64 tg = ((u64)(u32)(t + 1)) << 32;
            AST(dstb,       tg | (u64)(u32)uu.u[0]);
            AST(dstb + 64,  tg | (uu.u[0] >> 32));
            AST(dstb + 128, tg | (u64)(u32)uu.u[1]);
            AST(dstb + 192, tg | (uu.u[1] >> 32));
            u64* q = &hlds[(jw * 4 + w) * 128 + lane * 2];   // self short-circuit
            q[0] = uu.u[0];
            q[1] = uu.u[1];
        }
        // no drain, no seqno: each tagged word self-attests on arrival

        // off critical path: fp32 outputs + next xproj prefetch (overlap poll)
#pragma unroll
        for (int r = 0; r < 4; r++) {
            const int bg = g * 16 + bq + r;
            float* o = out + (bg * TT + t) * HH + col0;
            o[0]  = hv[0][r];
            o[16] = hv[1][r];
            if (t == TT - 1) {
                float* o2 = out + OUT_MAIN + bg * HH + col0;
                o2[0]  = hv[0][r];
                o2[16] = hv[1][r];
            }
        }
        if (t + 1 < TT) {
#pragma unroll
            for (int r = 0; r < 4; r++) {
                const float* xs = out + ((g * 16 + bq + r) * TT + (t + 1)) * HH + col0;
                xp[0][r] = xs[0];
                xp[1][r] = xs[16];
            }
        }
    }
}

// ---------------------------------------------------------------------------
extern "C" void kernel_launch(void* const* d_in, const int* in_sizes, int n_in,
                              void* d_out, int out_size, void* d_ws, size_t ws_size,
                              hipStream_t stream) {
    const float* seq       = (const float*)d_in[0];
    const float* w_ih      = (const float*)d_in[1];
    const float* w_ih_mask = (const float*)d_in[2];
    const float* w_hh      = (const float*)d_in[3];
    const float* w_hh_mask = (const float*)d_in[4];
    const float* b_ih      = (const float*)d_in[5];
    const float* b_ih_mask = (const float*)d_in[6];
    const float* b_hh      = (const float*)d_in[7];
    const float* b_hh_mask = (const float*)d_in[8];

    float* out = (float*)d_out;
    char*  ws  = (char*)d_ws;
    _Float16* Wih  = (_Float16*)(ws + OFF_WIH);
    _Float16* Whh  = (_Float16*)(ws + OFF_WHH);
    float*    bias = (float*)(ws + OFF_BIAS);
    u64*      hbt  = (u64*)(ws + OFF_HBUF);

    prep_kernel<<<dim3(4096), dim3(256), 0, stream>>>(w_ih, w_ih_mask, w_hh, w_hh_mask,
                                                      b_ih, b_ih_mask, b_hh, b_hh_mask,
                                                      Wih, Whh, bias, hbt);
    gemm_xproj<<<dim3(2048), dim3(256), 0, stream>>>(seq, Wih, bias, out);
    rnn_steps<<<dim3(32), dim3(256), 0, stream>>>(Whh, out, hbt);
}

// Round 9
// 2174.211 us; speedup vs baseline: 1.3316x; 1.3316x over previous
//
#include <hip/hip_runtime.h>
#include <cmath>

// ---------------------------------------------------------------------------
// RegRNN: out[b,t,:] = h_t ; h_t = tanh(xproj[b,t,:] + h_{t-1} @ Whh^T)
// xproj = seq @ Wih^T + bias   (Wih/Whh hard-concrete gated, fp16)
//
// SINGLE fused kernel after prep:
//   bids 0..31   : persistent recurrence (round-7 protocol: per-wave seqno
//                  publish after vmcnt(0) drain; poll lanes 0..7; LDS-coop
//                  peer chunk staging; own slice short-circuit). EARLY
//                  PUBLISH: transpose tile is per-wave PRIVATE (80B rows),
//                  so chunk read + publish happen BEFORE barrier B.
//   bids 32..2079: xproj GEMM tiles, t-range-major order (trange=gbid>>9).
//                  C stored via agent-scope bypass stores (cross-XCD
//                  visible), then __syncthreads (vmcnt drain) + tid0
//                  atomicAdd on cnt[trange][g][njw] (target 16).
//   rnn gates xp prefetch on cnt only at t=0,128,256,384 -> GEMM overlaps
//   the recurrence except the first tranche (~90us). GEMM WGs never wait
//   on rnn => no deadlock; worst case (rnn dispatched late) = sequential.
// ---------------------------------------------------------------------------

typedef _Float16 v8h __attribute__((ext_vector_type(8)));
typedef float    v4f __attribute__((ext_vector_type(4)));
typedef unsigned long long u64;
typedef unsigned int u32;

#define BB 64
#define TT 512
#define HH 1024
#define OUT_MAIN (BB * TT * HH) // 33554432
// ws layout (bytes)
#define OFF_WIH  0u
#define OFF_WHH  (2u << 20)
#define OFF_BIAS (4u << 20)
#define OFF_HBUF ((4u << 20) + 8192u)            // 2 par * 4 groups * 16384 halves = 256KB
#define OFF_SEQF ((4u << 20) + 8192u + 262144u)  // 256 ints
#define OFF_CNT  ((4u << 20) + 8192u + 262144u + 1024u) // 128 ints

#define ALD(p)    __hip_atomic_load((p),        __ATOMIC_RELAXED, __HIP_MEMORY_SCOPE_AGENT)
#define AST(p, v) __hip_atomic_store((p), (v),  __ATOMIC_RELAXED, __HIP_MEMORY_SCOPE_AGENT)

__device__ __forceinline__ float hc_gate(float x) {
    float s = 1.0f / (1.0f + __expf(-x));
    float g = s * 1.2f - 0.1f;              // sigmoid*(LB-LA)+LA
    return fminf(1.0f, fmaxf(0.0f, g));
}

__device__ __forceinline__ float fast_tanh(float x) {
    // tanh(x) = 1 - 2/(e^{2x}+1); exp->inf and ->0 both saturate correctly.
    float e = __expf(2.0f * x);
    return 1.0f - 2.0f * __builtin_amdgcn_rcpf(e + 1.0f);
}

// ---------------- prep: gate+cast weights, bias, zero h/seq/cnt ------------
__global__ void prep_kernel(const float* __restrict__ w_ih, const float* __restrict__ w_ih_mask,
                            const float* __restrict__ w_hh, const float* __restrict__ w_hh_mask,
                            const float* __restrict__ b_ih, const float* __restrict__ b_ih_mask,
                            const float* __restrict__ b_hh, const float* __restrict__ b_hh_mask,
                            _Float16* __restrict__ Wih, _Float16* __restrict__ Whh,
                            float* __restrict__ bias, _Float16* __restrict__ hbuf,
                            int* __restrict__ seqf, int* __restrict__ cnt) {
    const int idx = blockIdx.x * 256 + threadIdx.x;   // grid 4096*256 = 1048576 exact
    Wih[idx] = (_Float16)(hc_gate(w_ih_mask[idx]) * w_ih[idx]);
    Whh[idx] = (_Float16)(hc_gate(w_hh_mask[idx]) * w_hh[idx]);
    if (idx < HH)
        bias[idx] = hc_gate(b_ih_mask[idx]) * b_ih[idx] + hc_gate(b_hh_mask[idx]) * b_hh[idx];
    if (idx < 131072) hbuf[idx] = (_Float16)0.0f;     // both parities zeroed (h0 = 0)
    if (idx < 256) seqf[idx] = 0;                     // all seqnos = 0 (t=0 passes)
    if (idx < 128) cnt[idx] = 0;                      // gemm tranche counters
}

// ---------------- fused: GEMM producer + persistent recurrence -------------
__global__ __launch_bounds__(256, 1) void fused_kernel(
        const float* __restrict__ seq, const _Float16* __restrict__ Wih,
        const _Float16* __restrict__ Whh, const float* __restrict__ bias,
        float* __restrict__ out, _Float16* __restrict__ hbuf,
        int* __restrict__ seqf, int* __restrict__ cnt) {
    __shared__ __align__(16) char smem[38912];

    const int tid  = threadIdx.x;
    const int lane = tid & 63;
    const int w    = tid >> 6;

    if (blockIdx.x >= 32) {
        // ================= GEMM path =================
        // C[m,n] = sum_k seq[m,k]*Wih[n,k] + bias[n], 128x128 tile, BK=32.
        _Float16 (*As)[40] = (_Float16 (*)[40])smem;            // 10240 B
        _Float16 (*Bs)[40] = (_Float16 (*)[40])(smem + 10240);  // 10240 B

        const int gbid   = blockIdx.x - 32;
        const int trange = gbid >> 9;        // 0..3 (t-range of 128 steps)
        const int rem    = gbid & 511;
        const int bb     = rem >> 3;         // batch 0..63
        const int njw    = rem & 7;          // n-slice 0..7
        const int m0 = bb * 512 + trange * 128;
        const int n0 = njw * 128;
        const int mw = (w >> 1) * 64, nw = (w & 1) * 64;

        const int sr = tid >> 1;             // staging row 0..127
        const int sc = (tid & 1) * 16;       // staging col 0/16

        const float*    aSrc = seq + (m0 + sr) * HH + sc;
        const _Float16* bSrc = Wih + (n0 + sr) * HH + sc;

        const v4f vzero = {0.f, 0.f, 0.f, 0.f};
        v4f acc[4][4];
#pragma unroll
        for (int i = 0; i < 4; i++)
#pragma unroll
            for (int j = 0; j < 4; j++) acc[i][j] = vzero;

        const int arow = mw + (lane & 15);
        const int brow = nw + (lane & 15);
        const int kq   = (lane >> 4) * 8;

        for (int k0 = 0; k0 < HH; k0 += 32) {
            float4 f0 = *(const float4*)(aSrc + 0);
            float4 f1 = *(const float4*)(aSrc + 4);
            float4 f2 = *(const float4*)(aSrc + 8);
            float4 f3 = *(const float4*)(aSrc + 12);
            v8h a0 = {(_Float16)f0.x, (_Float16)f0.y, (_Float16)f0.z, (_Float16)f0.w,
                      (_Float16)f1.x, (_Float16)f1.y, (_Float16)f1.z, (_Float16)f1.w};
            v8h a1 = {(_Float16)f2.x, (_Float16)f2.y, (_Float16)f2.z, (_Float16)f2.w,
                      (_Float16)f3.x, (_Float16)f3.y, (_Float16)f3.z, (_Float16)f3.w};
            v8h b0 = *(const v8h*)(bSrc + 0);
            v8h b1 = *(const v8h*)(bSrc + 8);
            *(v8h*)&As[sr][sc]     = a0;
            *(v8h*)&As[sr][sc + 8] = a1;
            *(v8h*)&Bs[sr][sc]     = b0;
            *(v8h*)&Bs[sr][sc + 8] = b1;
            __syncthreads();

            v8h af[4], bf[4];
#pragma unroll
            for (int mi = 0; mi < 4; mi++) af[mi] = *(const v8h*)&As[mi * 16 + arow][kq];
#pragma unroll
            for (int ni = 0; ni < 4; ni++) bf[ni] = *(const v8h*)&Bs[ni * 16 + brow][kq];
#pragma unroll
            for (int mi = 0; mi < 4; mi++)
#pragma unroll
                for (int ni = 0; ni < 4; ni++)
                    acc[mi][ni] = __builtin_amdgcn_mfma_f32_16x16x32_f16(af[mi], bf[ni], acc[mi][ni], 0, 0, 0);
            __syncthreads();
            aSrc += 32;
            bSrc += 32;
        }

        // epilogue: agent-scope bypass stores (cross-XCD visible in-kernel)
        const int colb = lane & 15;
        const int rowq = (lane >> 4) * 4;
#pragma unroll
        for (int ni = 0; ni < 4; ni++) {
            const int col = n0 + nw + ni * 16 + colb;
            const float bz = bias[col];
#pragma unroll
            for (int mi = 0; mi < 4; mi++) {
                const int row = m0 + mw + mi * 16 + rowq;
#pragma unroll
                for (int r = 0; r < 4; r++) {
                    union { float f; u32 u; } cv;
                    cv.f = acc[mi][ni][r] + bz;
                    AST((u32*)&out[(row + r) * HH + col], cv.u);
                }
            }
        }
        __syncthreads();   // implicit vmcnt(0): all WG stores at coherence pt
        if (tid == 0)
            __hip_atomic_fetch_add(&cnt[trange * 32 + (bb >> 4) * 8 + njw], 1,
                                   __ATOMIC_RELAXED, __HIP_MEMORY_SCOPE_AGENT);
        return;
    }

    // ================= RNN path =================
    // 32 WGs: g = bid>>3 (16 batches), jw = bid&7 (128 cols).
    // hbuf chunk c = 1024B = 128 u64 (offsets applied POST u64-cast).
    u64*      hlds  = (u64*)smem;                    // 32 KB fragment-ready h
    _Float16* tbase = (_Float16*)(smem + 32768);     // 4 waves * 16 rows * 80B

    const int bid = blockIdx.x;
    const int g   = bid >> 3;
    const int jw  = bid & 7;

    const int l15 = lane & 15;
    const int kq  = (lane >> 4) * 8;
    const int bq  = (lane >> 4) * 4;

    const int col0 = jw * 128 + w * 32 + l15;

    // Whh fragments: Wf[c*2+ni] = Whh[(col0+16*ni)*1024 + c*32 + kq .. +8]
    v8h Wf[64];
    {
        const _Float16* w0 = Whh + col0 * 1024 + kq;
        const _Float16* w1 = Whh + (col0 + 16) * 1024 + kq;
#pragma unroll
        for (int c = 0; c < 32; c++) {
            Wf[c * 2 + 0] = *(const v8h*)(w0 + c * 32);
            Wf[c * 2 + 1] = *(const v8h*)(w1 + c * 32);
        }
    }

    // own-slice hlds init (h0 = 0)
    {
        u64* q = &hlds[(jw * 4 + w) * 128 + lane * 2];
        q[0] = 0ull; q[1] = 0ull;
    }

    // wait tranche 0, then prefetch xp for t=0 (bypass loads: gemm wrote L3)
    {
        const int* c0 = &cnt[0 * 32 + g * 8 + jw];
        while (ALD(c0) < 16) __builtin_amdgcn_s_sleep(8);
        asm volatile("" ::: "memory");
    }
    float xp[2][4];
#pragma unroll
    for (int r = 0; r < 4; r++) {
        const u32* xs = (const u32*)(out + ((g * 16 + bq + r) * TT + 0) * HH + col0);
        union { u32 u; float f; } v0, v1;
        v0.u = ALD(xs); v1.u = ALD(xs + 16);
        xp[0][r] = v0.f; xp[1][r] = v1.f;
    }

    const int pollIdx = (lane < 8 && lane != jw) ? (lane * 4 + w) : -1;
    _Float16* tw = tbase + w * 640;   // private 16x40-half tile (80B rows)

    for (int t = 0; t < TT; t++) {
        // ---- per-wave poll: 7 peer chunk-row-w seqnos (parity t&1)
        int* sqp = seqf + ((t & 1) * 4 + g) * 32;
        for (;;) {
            int ok = 1;
            if (pollIdx >= 0) ok = (ALD(sqp + pollIdx) >= t) ? 1 : 0;
            if (__all(ok)) break;
            __builtin_amdgcn_s_sleep(1);
        }
        asm volatile("" ::: "memory");

        // ---- load 7 peers' chunk-row w -> hlds (own slice short-circuited)
        {
            const u64* hbp = (const u64*)(hbuf + ((t & 1) * 4 + g) * 16384);
            u64 dv[16];
#pragma unroll
            for (int i = 0; i < 8; i++) {
                if (i != jw) {
                    const u64* p = hbp + (i * 4 + w) * 128 + lane * 2;
                    dv[2 * i]     = ALD(p);
                    dv[2 * i + 1] = ALD(p + 1);
                }
            }
#pragma unroll
            for (int i = 0; i < 8; i++) {
                if (i != jw) {
                    u64* q = &hlds[(i * 4 + w) * 128 + lane * 2];
                    q[0] = dv[2 * i];
                    q[1] = dv[2 * i + 1];
                }
            }
        }
        __syncthreads();   // D: full h_{t-1} staged in hlds

        // ---- MFMA over 32 chunks from LDS
        v4f aA0 = {0.f, 0.f, 0.f, 0.f}, aA1 = aA0, aB0 = aA0, aB1 = aA0;
#pragma unroll
        for (int cc = 0; cc < 8; cc++) {
            const u64* q = &hlds[cc * 512 + lane * 2];
            v8h h0 = *(const v8h*)(q);
            v8h h1 = *(const v8h*)(q + 128);
            v8h h2 = *(const v8h*)(q + 256);
            v8h h3 = *(const v8h*)(q + 384);
            aA0 = __builtin_amdgcn_mfma_f32_16x16x32_f16(h0, Wf[(cc * 4 + 0) * 2 + 0], aA0, 0, 0, 0);
            aA1 = __builtin_amdgcn_mfma_f32_16x16x32_f16(h0, Wf[(cc * 4 + 0) * 2 + 1], aA1, 0, 0, 0);
            aB0 = __builtin_amdgcn_mfma_f32_16x16x32_f16(h1, Wf[(cc * 4 + 1) * 2 + 0], aB0, 0, 0, 0);
            aB1 = __builtin_amdgcn_mfma_f32_16x16x32_f16(h1, Wf[(cc * 4 + 1) * 2 + 1], aB1, 0, 0, 0);
            aA0 = __builtin_amdgcn_mfma_f32_16x16x32_f16(h2, Wf[(cc * 4 + 2) * 2 + 0], aA0, 0, 0, 0);
            aA1 = __builtin_amdgcn_mfma_f32_16x16x32_f16(h2, Wf[(cc * 4 + 2) * 2 + 1], aA1, 0, 0, 0);
            aB0 = __builtin_amdgcn_mfma_f32_16x16x32_f16(h3, Wf[(cc * 4 + 3) * 2 + 0], aB0, 0, 0, 0);
            aB1 = __builtin_amdgcn_mfma_f32_16x16x32_f16(h3, Wf[(cc * 4 + 3) * 2 + 1], aB1, 0, 0, 0);
        }
        const v4f av0 = aA0 + aB0;
        const v4f av1 = aA1 + aB1;

        // ---- tanh + PRIVATE tile transpose (no cross-wave bytes)
        float hv[2][4];
#pragma unroll
        for (int r = 0; r < 4; r++) {
            hv[0][r] = fast_tanh(xp[0][r] + av0[r]);
            hv[1][r] = fast_tanh(xp[1][r] + av1[r]);
            const int row = bq + r;
            tw[row * 40 + l15]      = (_Float16)hv[0][r];
            tw[row * 40 + 16 + l15] = (_Float16)hv[1][r];
        }
        // intra-wave read-back (ds ordering within wave; lgkmcnt by compiler)
        union { v8h v; u64 u[2]; } U;
        U.v = *(const v8h*)(tw + (lane & 15) * 40 + (lane >> 4) * 8);

        // ---- EARLY PUBLISH (before barrier B): own chunk + seqno
        if (t + 1 < TT) {
            u64* dst = (u64*)(hbuf + (((t + 1) & 1) * 4 + g) * 16384) + (jw * 4 + w) * 128 + lane * 2;
            AST(dst,     U.u[0]);
            AST(dst + 1, U.u[1]);
            asm volatile("s_waitcnt vmcnt(0)" ::: "memory");
            if (lane == 0)
                AST(seqf + (((t + 1) & 1) * 4 + g) * 32 + jw * 4 + w, t + 1);
        }
        __syncthreads();   // B: all waves' MFMA done -> hlds self-write safe

        {
            u64* q = &hlds[(jw * 4 + w) * 128 + lane * 2];   // self short-circuit
            q[0] = U.u[0];
            q[1] = U.u[1];
        }

        // ---- off critical path: outputs + next xproj prefetch
#pragma unroll
        for (int r = 0; r < 4; r++) {
            const int bg = g * 16 + bq + r;
            float* o = out + (bg * TT + t) * HH + col0;
            o[0]  = hv[0][r];
            o[16] = hv[1][r];
            if (t == TT - 1) {
                float* o2 = out + OUT_MAIN + bg * HH + col0;
                o2[0]  = hv[0][r];
                o2[16] = hv[1][r];
            }
        }
        if (t + 1 < TT) {
            if (((t + 1) & 127) == 0) {   // tranche boundary: wait gemm tiles
                const int* cc = &cnt[((t + 1) >> 7) * 32 + g * 8 + jw];
                while (ALD(cc) < 16) __builtin_amdgcn_s_sleep(8);
                asm volatile("" ::: "memory");
            }
#pragma unroll
            for (int r = 0; r < 4; r++) {
                const u32* xs = (const u32*)(out + ((g * 16 + bq + r) * TT + (t + 1)) * HH + col0);
                union { u32 u; float f; } v0, v1;
                v0.u = ALD(xs); v1.u = ALD(xs + 16);
                xp[0][r] = v0.f; xp[1][r] = v1.f;
            }
        }
    }
}

// ---------------------------------------------------------------------------
extern "C" void kernel_launch(void* const* d_in, const int* in_sizes, int n_in,
                              void* d_out, int out_size, void* d_ws, size_t ws_size,
                              hipStream_t stream) {
    const float* seq       = (const float*)d_in[0];
    const float* w_ih      = (const float*)d_in[1];
    const float* w_ih_mask = (const float*)d_in[2];
    const float* w_hh      = (const float*)d_in[3];
    const float* w_hh_mask = (const float*)d_in[4];
    const float* b_ih      = (const float*)d_in[5];
    const float* b_ih_mask = (const float*)d_in[6];
    const float* b_hh      = (const float*)d_in[7];
    const float* b_hh_mask = (const float*)d_in[8];

    float* out = (float*)d_out;
    char*  ws  = (char*)d_ws;
    _Float16* Wih  = (_Float16*)(ws + OFF_WIH);
    _Float16* Whh  = (_Float16*)(ws + OFF_WHH);
    float*    bias = (float*)(ws + OFF_BIAS);
    _Float16* hbuf = (_Float16*)(ws + OFF_HBUF);
    int*      seqf = (int*)(ws + OFF_SEQF);
    int*      cnt  = (int*)(ws + OFF_CNT);

    prep_kernel<<<dim3(4096), dim3(256), 0, stream>>>(w_ih, w_ih_mask, w_hh, w_hh_mask,
                                                      b_ih, b_ih_mask, b_hh, b_hh_mask,
                                                      Wih, Whh, bias, hbuf, seqf, cnt);
    fused_kernel<<<dim3(2080), dim3(256), 0, stream>>>(seq, Wih, Whh, bias, out,
                                                       hbuf, seqf, cnt);
}